// Round 6
// baseline (190.407 us; speedup 1.0000x reference)
//
#include <hip/hip_runtime.h>

#define DIM 256
#define NHEADS 8
#define HDIM 32

typedef _Float16 half8_t __attribute__((ext_vector_type(8)));
typedef _Float16 half4_t __attribute__((ext_vector_type(4)));
typedef float float4_t __attribute__((ext_vector_type(4)));

// ---------------------------------------------------------------------------
// prep: (a) x fp32 -> fp16 flat; (b) Wqkv [256,768] -> WqT [768,256] fp16;
//       (c) Wout [256,256] -> WoT [256,256] fp16 (transposed for B-frags).
// ---------------------------------------------------------------------------
__global__ __launch_bounds__(256) void prep(const float* __restrict__ x,
                                            const float* __restrict__ Wqkv,
                                            const float* __restrict__ Wout,
                                            _Float16* __restrict__ xh,
                                            _Float16* __restrict__ WqT,
                                            _Float16* __restrict__ WoT) {
    __shared__ float ts[32][33];
    const int bid = blockIdx.x, t = threadIdx.x;
    if (bid < 1024) {
        size_t idx = (size_t)bid * 2048 + (size_t)t * 8;
        float tmp[8];
        *reinterpret_cast<float4*>(tmp)     = *reinterpret_cast<const float4*>(x + idx);
        *reinterpret_cast<float4*>(tmp + 4) = *reinterpret_cast<const float4*>(x + idx + 4);
        half8_t h;
        #pragma unroll
        for (int j = 0; j < 8; ++j) h[j] = (_Float16)tmp[j];
        *reinterpret_cast<half8_t*>(xh + idx) = h;
    } else {
        const float* src; _Float16* dst; int K, N, kb, nb;
        if (bid < 1024 + 192) { int b2 = bid - 1024; src = Wqkv; dst = WqT; K = 256; N = 768; nb = b2 % 24; kb = b2 / 24; }
        else                  { int b3 = bid - 1216; src = Wout; dst = WoT; K = 256; N = 256; nb = b3 % 8;  kb = b3 / 8; }
        const int tx = t & 31, ty = t >> 5;
        #pragma unroll
        for (int i = 0; i < 4; ++i) {
            int k = kb * 32 + ty + i * 8;
            ts[ty + i * 8][tx] = src[(size_t)k * N + nb * 32 + tx];
        }
        __syncthreads();
        #pragma unroll
        for (int i = 0; i < 4; ++i) {
            int nl = ty + i * 8;
            dst[(size_t)(nb * 32 + nl) * K + kb * 32 + tx] = (_Float16)ts[tx][nl];
        }
    }
}

// ---------------------------------------------------------------------------
// LDS-free fp16 MFMA GEMM with register prefetch (depth 1) on the k-loop.
// Tile = 64 x BN, 4 waves; wave quadrant 32 x (BN/2). Frags direct-global.
// VSPLIT (gemm1): n-blocks with n0>=512 (V of QKV) stored TRANSPOSED to
// VT[b][h][hd][token]. COMBINE (gemm2): A synthesized from 2 key-split
// partials, A = (N0+N1)*rcp(D0+D1+eps); reciprocals hoisted out of the loop.
// ---------------------------------------------------------------------------
template <int BN, bool OUT_HALF, bool VSPLIT, bool COMBINE>
__global__ __launch_bounds__(256, 4) void gemm_g(const _Float16* __restrict__ A,
                                                 const _Float16* __restrict__ BT,
                                                 const float* __restrict__ bias,
                                                 void* __restrict__ Cv,
                                                 _Float16* __restrict__ VTo,
                                                 const _Float16* __restrict__ N0,
                                                 const float* __restrict__ DENc,
                                                 int M, int N, int K, int ldc) {
    constexpr int NF = BN / 32;           // n-frags per wave
    const int t = threadIdx.x, lane = t & 63, wave = t >> 6;
    const int l16 = lane & 15, quad = lane >> 4;
    const int m0 = blockIdx.y * 64, n0 = blockIdx.x * BN;
    const int wr = (wave >> 1) * 32, wc = (wave & 1) * (BN / 2);
    const int bb = m0 >> 11;

    float4_t acc[2][NF];
    #pragma unroll
    for (int i = 0; i < 2; ++i)
        #pragma unroll
        for (int j = 0; j < NF; ++j) acc[i][j] = (float4_t){0.f, 0.f, 0.f, 0.f};

    // COMBINE: hoist per-row reciprocal denominators (8 heads x 2 row-frags).
    float rj[2][8];
    if constexpr (COMBINE) {
        #pragma unroll
        for (int i = 0; i < 2; ++i) {
            int row = (m0 & 2047) + wr + i * 16 + l16;
            #pragma unroll
            for (int hh = 0; hh < 8; ++hh) {
                int di = (bb * 8 + hh) * 2048 + row;
                rj[i][hh] = 1.f / (DENc[di] + DENc[di + 65536] + 1e-6f);
            }
        }
    }

    const _Float16* ap0 = nullptr;
    const _Float16* np0 = nullptr;
    if constexpr (COMBINE) np0 = N0 + (size_t)(m0 + wr + l16) * 256 + quad * 8;
    else                   ap0 = A  + (size_t)(m0 + wr + l16) * K + quad * 8;
    const _Float16* bp0 = BT + (size_t)(n0 + wc + l16) * K + quad * 8;

    // prefetch buffers (raw loads only; COMBINE arithmetic happens at use)
    half8_t pa0[2], pa1[2], pb[NF];
    auto loadA = [&](int k0, half8_t* a0, half8_t* a1) {
        if constexpr (COMBINE) {
            #pragma unroll
            for (int i = 0; i < 2; ++i) {
                const _Float16* p = np0 + (size_t)i * 16 * 256 + k0;
                a0[i] = *reinterpret_cast<const half8_t*>(p);
                a1[i] = *reinterpret_cast<const half8_t*>(p + 2097152);
            }
        } else {
            #pragma unroll
            for (int i = 0; i < 2; ++i)
                a0[i] = *reinterpret_cast<const half8_t*>(ap0 + (size_t)i * 16 * K + k0);
        }
    };
    auto loadB = [&](int k0, half8_t* b) {
        #pragma unroll
        for (int j = 0; j < NF; ++j)
            b[j] = *reinterpret_cast<const half8_t*>(bp0 + (size_t)j * 16 * K + k0);
    };
    loadA(0, pa0, pa1);
    loadB(0, pb);

    #pragma unroll
    for (int k0 = 0; k0 < K; k0 += 32) {
        half8_t na0[2], na1[2], nb[NF];
        const int kn = (k0 + 32 < K) ? k0 + 32 : 0;
        loadA(kn, na0, na1);
        loadB(kn, nb);

        half8_t a[2];
        if constexpr (COMBINE) {
            const int hh = k0 >> 5;
            #pragma unroll
            for (int i = 0; i < 2; ++i)
                a[i] = (pa0[i] + pa1[i]) * (_Float16)rj[i][hh];
        } else {
            a[0] = pa0[0]; a[1] = pa0[1];
        }
        #pragma unroll
        for (int i = 0; i < 2; ++i)
            #pragma unroll
            for (int j = 0; j < NF; ++j)
                acc[i][j] = __builtin_amdgcn_mfma_f32_16x16x32_f16(a[i], pb[j], acc[i][j], 0, 0, 0);

        #pragma unroll
        for (int i = 0; i < 2; ++i) { pa0[i] = na0[i]; pa1[i] = na1[i]; }
        #pragma unroll
        for (int j = 0; j < NF; ++j) pb[j] = nb[j];
    }

    if (VSPLIT && n0 >= 512) {
        // V part: write transposed VT[b][h][hd][token], 4 tokens per b64 store.
        const int tok0 = (m0 & 2047) + wr;
        #pragma unroll
        for (int i = 0; i < 2; ++i)
            #pragma unroll
            for (int j = 0; j < NF; ++j) {
                int vcol = n0 + wc + j * 16 + l16 - 512;
                int hh = vcol >> 5, d = vcol & 31;
                half4_t p;
                #pragma unroll
                for (int r = 0; r < 4; ++r) p[r] = (_Float16)acc[i][j][r];
                *reinterpret_cast<half4_t*>(
                    VTo + ((size_t)(bb * NHEADS + hh) * HDIM + d) * 2048
                        + tok0 + i * 16 + quad * 4) = p;
            }
    } else {
        #pragma unroll
        for (int i = 0; i < 2; ++i)
            #pragma unroll
            for (int r = 0; r < 4; ++r) {
                int row = m0 + wr + i * 16 + quad * 4 + r;
                #pragma unroll
                for (int j = 0; j < NF; ++j) {
                    int col = n0 + wc + j * 16 + l16;
                    float v = acc[i][j][r] + (bias ? bias[col] : 0.f);
                    if (OUT_HALF) ((_Float16*)Cv)[(size_t)row * ldc + col] = (_Float16)v;
                    else          ((float*)Cv)[(size_t)row * ldc + col] = v;
                }
            }
    }
}

// ---------------------------------------------------------------------------
// MFMA flash attention v5: key-split x2 + explicit software pipeline.
// Grid: 1024 blocks = (b,h) x 16 q-blocks(128) x 2 key-halves(1024).
// 4 waves, 32 q each. Zero barriers. Per 64-key iteration:
//   - NEXT iteration's 4 K-frags prefetched at loop top (reg double-buffer);
//   - current V-frags (4) issued at loop top, consumed after the exp block;
//   - S^T = mfma(kf,qf); e=exp(s*scale); E half4 -> per-wave es[32][40]
//     (ds_write_b64), A-frags back via ds_read_b128; PV MFMAs.
// Partials: NUM fp16 (unnormalized), DEN fp32; combined in gemm2's A load.
// ---------------------------------------------------------------------------
__global__ __launch_bounds__(256, 4) void attn_v5(const _Float16* __restrict__ qkh,
                                                  const _Float16* __restrict__ VT,
                                                  _Float16* __restrict__ NUM,
                                                  float* __restrict__ DEN) {
    __shared__ alignas(16) _Float16 es[4][32][40];
    const int bid = blockIdx.x;
    const int kh = bid & 1;
    const int qb = (bid >> 1) & 15;
    const int bh = bid >> 5;
    const int b = bh >> 3, h = bh & 7;
    const int t = threadIdx.x, lane = t & 63, wave = t >> 6;
    const int l16 = lane & 15, quad = lane >> 4;
    const float scale = 0.17677669529663687f;  // 32^-0.5
    const int bN = b * 2048;
    const int q0w = qb * 128 + wave * 32;
    const int kbeg = kh * 1024;

    const _Float16* qrow = qkh + (size_t)(bN + q0w + l16) * 512 + h * HDIM + quad * 8;
    half8_t qf0 = *reinterpret_cast<const half8_t*>(qrow);
    half8_t qf1 = *reinterpret_cast<const half8_t*>(qrow + (size_t)16 * 512);

    const _Float16* kbase = qkh + (size_t)(bN + l16) * 512 + 256 + h * HDIM + quad * 8;
    const _Float16* vbase = VT + (size_t)bh * HDIM * 2048 + (size_t)l16 * 2048 + quad * 8;

    float4_t num[2][2];
    #pragma unroll
    for (int g = 0; g < 2; ++g)
        #pragma unroll
        for (int dt = 0; dt < 2; ++dt) num[g][dt] = (float4_t){0.f, 0.f, 0.f, 0.f};
    float ds[2] = {0.f, 0.f};
    _Float16* esw = &es[wave][0][0];
    const float4_t z = {0.f, 0.f, 0.f, 0.f};

    auto loadK = [&](int k0, half8_t* dst) {
        const _Float16* kp = kbase + (size_t)k0 * 512;
        dst[0] = *reinterpret_cast<const half8_t*>(kp);
        dst[1] = *reinterpret_cast<const half8_t*>(kp + (size_t)16 * 512);
        dst[2] = *reinterpret_cast<const half8_t*>(kp + (size_t)32 * 512);
        dst[3] = *reinterpret_cast<const half8_t*>(kp + (size_t)48 * 512);
    };
    auto loadV = [&](int k0, half8_t* dst) {
        const _Float16* vp = vbase + k0;
        dst[0] = *reinterpret_cast<const half8_t*>(vp);                       // s0 hd0-15
        dst[1] = *reinterpret_cast<const half8_t*>(vp + (size_t)16 * 2048);   // s0 hd16-31
        dst[2] = *reinterpret_cast<const half8_t*>(vp + 32);                  // s1 hd0-15
        dst[3] = *reinterpret_cast<const half8_t*>(vp + 32 + (size_t)16 * 2048);
    };

    half8_t kf[4];
    loadK(kbeg, kf);   // prologue

    #pragma unroll 2
    for (int it = 0; it < 16; ++it) {
        const int k0 = kbeg + it * 64;
        const int kn = kbeg + ((it + 1) & 15) * 64;   // wraps on last iter (discarded)

        // issue next-K and current-V loads before any compute
        half8_t nkf[4], vf[4];
        loadK(kn, nkf);
        loadV(k0, vf);

        // S^T = K Q^T : lane holds S^T[key=kb*16+quad*4+r][q=q0w+g*16+l16]
        float4_t st[4][2];
        #pragma unroll
        for (int kb = 0; kb < 4; ++kb) {
            st[kb][0] = __builtin_amdgcn_mfma_f32_16x16x32_f16(kf[kb], qf0, z, 0, 0, 0);
            st[kb][1] = __builtin_amdgcn_mfma_f32_16x16x32_f16(kf[kb], qf1, z, 0, 0, 0);
        }

        // e = exp(s*scale); accumulate denom; pack fp16 half4 per (kb,g).
        half4_t ep[4][2];
        #pragma unroll
        for (int kb = 0; kb < 4; ++kb)
            #pragma unroll
            for (int g = 0; g < 2; ++g)
                #pragma unroll
                for (int r = 0; r < 4; ++r) {
                    float e = __expf(st[kb][g][r] * scale);
                    ds[g] += e;
                    ep[kb][g][r] = (_Float16)e;
                }

        // Two 32-k chunks: E -> LDS (b64), E A-frag back (b128), PV MFMAs.
        #pragma unroll
        for (int s = 0; s < 2; ++s) {
            #pragma unroll
            for (int tt = 0; tt < 2; ++tt)
                #pragma unroll
                for (int g = 0; g < 2; ++g)
                    *reinterpret_cast<half4_t*>(
                        esw + (g * 16 + l16) * 40 + tt * 16 + quad * 4) = ep[s * 2 + tt][g];

            half8_t ef0 = *reinterpret_cast<const half8_t*>(esw + l16 * 40 + quad * 8);
            half8_t ef1 = *reinterpret_cast<const half8_t*>(esw + (16 + l16) * 40 + quad * 8);

            num[0][0] = __builtin_amdgcn_mfma_f32_16x16x32_f16(ef0, vf[s * 2],     num[0][0], 0, 0, 0);
            num[0][1] = __builtin_amdgcn_mfma_f32_16x16x32_f16(ef0, vf[s * 2 + 1], num[0][1], 0, 0, 0);
            num[1][0] = __builtin_amdgcn_mfma_f32_16x16x32_f16(ef1, vf[s * 2],     num[1][0], 0, 0, 0);
            num[1][1] = __builtin_amdgcn_mfma_f32_16x16x32_f16(ef1, vf[s * 2 + 1], num[1][1], 0, 0, 0);
        }

        #pragma unroll
        for (int j = 0; j < 4; ++j) kf[j] = nkf[j];
    }

    // denom partial: complete per-q sums (4 key-quads) via 2 shfls.
    #pragma unroll
    for (int g = 0; g < 2; ++g) {
        ds[g] += __shfl_xor(ds[g], 16, 64);
        ds[g] += __shfl_xor(ds[g], 32, 64);
    }

    // Store partial numerator (fp16, no rcp) and partial denominator (fp32).
    _Float16* ob = NUM + (size_t)kh * 2097152 + (size_t)(bN + q0w) * DIM + h * HDIM;
    #pragma unroll
    for (int g = 0; g < 2; ++g)
        #pragma unroll
        for (int r = 0; r < 4; ++r) {
            size_t ro = (size_t)(g * 16 + quad * 4 + r) * DIM;
            ob[ro + l16]      = (_Float16)num[g][0][r];
            ob[ro + 16 + l16] = (_Float16)num[g][1][r];
        }
    if (quad == 0) {
        DEN[kh * 65536 + bh * 2048 + q0w + l16]      = ds[0];
        DEN[kh * 65536 + bh * 2048 + q0w + 16 + l16] = ds[1];
    }
}

extern "C" void kernel_launch(void* const* d_in, const int* in_sizes, int n_in,
                              void* d_out, int out_size, void* d_ws, size_t ws_size,
                              hipStream_t stream) {
    const float* x    = (const float*)d_in[0];
    const float* Wqkv = (const float*)d_in[1];
    const float* Wout = (const float*)d_in[2];
    const float* bout = (const float*)d_in[3];
    float* out = (float*)d_out;
    const int M = 8192;

    _Float16* xh  = (_Float16*)d_ws;                 // [8192,256]
    _Float16* WqT = xh + (size_t)M * DIM;            // [768,256]
    _Float16* WoT = WqT + 768 * 256;                 // [256,256]
    _Float16* qkh = WoT + 256 * 256;                 // [8192,512]  (Q|K)
    _Float16* vt  = qkh + (size_t)M * 512;           // [4][8][32][2048] V^T
    _Float16* NUM = vt + (size_t)32 * HDIM * 2048;   // [2][8192,256] partials
    float*    DEN = (float*)(NUM + (size_t)2 * M * DIM);  // [2][65536]

    hipLaunchKernelGGL(prep, dim3(1280), dim3(256), 0, stream, x, Wqkv, Wout, xh, WqT, WoT);
    // qkv GEMM: Q,K -> qkh (ldc 512); V -> vt transposed.
    hipLaunchKernelGGL((gemm_g<64, true, true, false>), dim3(12, 128), dim3(256), 0, stream,
                       xh, WqT, (const float*)nullptr, (void*)qkh, vt,
                       (const _Float16*)nullptr, (const float*)nullptr, M, 768, DIM, 512);
    // attention, key-split x2 -> partials
    hipLaunchKernelGGL(attn_v5, dim3(1024), dim3(256), 0, stream, qkh, vt, NUM, DEN);
    // out = combine(NUM,DEN) @ Wout + bout (fp32 out), 64x32 tiles
    hipLaunchKernelGGL((gemm_g<32, false, false, true>), dim3(8, 128), dim3(256), 0, stream,
                       (const _Float16*)nullptr, WoT, bout, (void*)out,
                       (_Float16*)nullptr, NUM, DEN, M, DIM, DIM, DIM);
}

// Round 7
// 125.313 us; speedup vs baseline: 1.5194x; 1.5194x over previous
//
#include <hip/hip_runtime.h>

#define DIM 256
#define NHEADS 8
#define HDIM 32

typedef _Float16 half8_t __attribute__((ext_vector_type(8)));
typedef _Float16 half4_t __attribute__((ext_vector_type(4)));
typedef float float4_t __attribute__((ext_vector_type(4)));

__device__ __forceinline__ void gload_lds16(const void* g, void* l) {
    __builtin_amdgcn_global_load_lds((const __attribute__((address_space(1))) void*)g,
                                     (__attribute__((address_space(3))) void*)l,
                                     16, 0, 0);
}

// ---------------------------------------------------------------------------
// prep: (a) x fp32 -> fp16 flat; (b) Wqkv [256,768] -> WqT [768,256] fp16;
//       (c) Wout [256,256] -> WoT [256,256] fp16 (transposed for B-frags).
// ---------------------------------------------------------------------------
__global__ __launch_bounds__(256) void prep(const float* __restrict__ x,
                                            const float* __restrict__ Wqkv,
                                            const float* __restrict__ Wout,
                                            _Float16* __restrict__ xh,
                                            _Float16* __restrict__ WqT,
                                            _Float16* __restrict__ WoT) {
    __shared__ float ts[32][33];
    const int bid = blockIdx.x, t = threadIdx.x;
    if (bid < 1024) {
        size_t idx = (size_t)bid * 2048 + (size_t)t * 8;
        float tmp[8];
        *reinterpret_cast<float4*>(tmp)     = *reinterpret_cast<const float4*>(x + idx);
        *reinterpret_cast<float4*>(tmp + 4) = *reinterpret_cast<const float4*>(x + idx + 4);
        half8_t h;
        #pragma unroll
        for (int j = 0; j < 8; ++j) h[j] = (_Float16)tmp[j];
        *reinterpret_cast<half8_t*>(xh + idx) = h;
    } else {
        const float* src; _Float16* dst; int K, N, kb, nb;
        if (bid < 1024 + 192) { int b2 = bid - 1024; src = Wqkv; dst = WqT; K = 256; N = 768; nb = b2 % 24; kb = b2 / 24; }
        else                  { int b3 = bid - 1216; src = Wout; dst = WoT; K = 256; N = 256; nb = b3 % 8;  kb = b3 / 8; }
        const int tx = t & 31, ty = t >> 5;
        #pragma unroll
        for (int i = 0; i < 4; ++i) {
            int k = kb * 32 + ty + i * 8;
            ts[ty + i * 8][tx] = src[(size_t)k * N + nb * 32 + tx];
        }
        __syncthreads();
        #pragma unroll
        for (int i = 0; i < 4; ++i) {
            int nl = ty + i * 8;
            dst[(size_t)(nb * 32 + nl) * K + kb * 32 + tx] = (_Float16)ts[tx][nl];
        }
    }
}

// ---------------------------------------------------------------------------
// fp16 MFMA GEMM, LDS-staged (R3 structure): C[M,N] = A[M,K] @ BT[N,K]^T.
// 128x128 tile, BK=32, 4 waves (64x64 each), global_load_lds 16B coalesced
// staging (contiguous 1KB per wave-DMA), fragments from LDS.
// VSPLIT (gemm1): tiles with n0>=512 are the V of QKV -> written TRANSPOSED
// to VT[b][h][hd][token] (half4 stores), not to C.
// ---------------------------------------------------------------------------
template <bool OUT_HALF, bool VSPLIT>
__global__ __launch_bounds__(256) void gemm_h(const _Float16* __restrict__ A,
                                              const _Float16* __restrict__ BT,
                                              const float* __restrict__ bias,
                                              void* __restrict__ Cv,
                                              _Float16* __restrict__ VTo,
                                              int M, int N, int K, int ldc) {
    __shared__ alignas(16) _Float16 As[128 * 32];
    __shared__ alignas(16) _Float16 Bs[128 * 32];
    const int t = threadIdx.x, lane = t & 63, wave = t >> 6;
    const int l16 = lane & 15, quad = lane >> 4;
    const int m0 = blockIdx.y * 128, n0 = blockIdx.x * 128;
    const int wr = (wave >> 1) * 64, wc = (wave & 1) * 64;
    float4_t acc[4][4];
    #pragma unroll
    for (int i = 0; i < 4; ++i)
        #pragma unroll
        for (int j = 0; j < 4; ++j) acc[i][j] = (float4_t){0.f, 0.f, 0.f, 0.f};

    const int srow = lane >> 2;        // 0..15 within 16-row chunk
    const int scol = (lane & 3) * 8;   // halves

    for (int k0 = 0; k0 < K; k0 += 32) {
        #pragma unroll
        for (int i = 0; i < 2; ++i) {
            int chunk = i * 4 + wave;          // 0..7, each = 16 rows
            int r = chunk * 16 + srow;
            gload_lds16(A  + (size_t)(m0 + r) * K + k0 + scol, As + chunk * 512);
            gload_lds16(BT + (size_t)(n0 + r) * K + k0 + scol, Bs + chunk * 512);
        }
        __syncthreads();
        half8_t af[4], bf[4];
        #pragma unroll
        for (int i = 0; i < 4; ++i)
            af[i] = *reinterpret_cast<const half8_t*>(As + (wr + i * 16 + l16) * 32 + quad * 8);
        #pragma unroll
        for (int j = 0; j < 4; ++j)
            bf[j] = *reinterpret_cast<const half8_t*>(Bs + (wc + j * 16 + l16) * 32 + quad * 8);
        #pragma unroll
        for (int i = 0; i < 4; ++i)
            #pragma unroll
            for (int j = 0; j < 4; ++j)
                acc[i][j] = __builtin_amdgcn_mfma_f32_16x16x32_f16(af[i], bf[j], acc[i][j], 0, 0, 0);
        __syncthreads();
    }

    if (VSPLIT && n0 >= 512) {
        // V tile: write transposed VT[b][h][hd][token], 4 tokens per b64 store.
        const int bb = m0 >> 11;
        const int tok0 = (m0 & 2047) + wr;
        #pragma unroll
        for (int i = 0; i < 4; ++i)
            #pragma unroll
            for (int j = 0; j < 4; ++j) {
                int vcol = n0 + wc + j * 16 + l16 - 512;
                int hh = vcol >> 5, d = vcol & 31;
                half4_t p;
                #pragma unroll
                for (int r = 0; r < 4; ++r) p[r] = (_Float16)acc[i][j][r];
                *reinterpret_cast<half4_t*>(
                    VTo + ((size_t)(bb * NHEADS + hh) * HDIM + d) * 2048
                        + tok0 + i * 16 + quad * 4) = p;
            }
    } else {
        float bv[4] = {0.f, 0.f, 0.f, 0.f};
        if (bias != nullptr) {
            #pragma unroll
            for (int j = 0; j < 4; ++j) bv[j] = bias[n0 + wc + j * 16 + l16];
        }
        #pragma unroll
        for (int i = 0; i < 4; ++i)
            #pragma unroll
            for (int r = 0; r < 4; ++r) {
                int row = m0 + wr + i * 16 + quad * 4 + r;
                #pragma unroll
                for (int j = 0; j < 4; ++j) {
                    int col = n0 + wc + j * 16 + l16;
                    float v = acc[i][j][r] + bv[j];
                    if (OUT_HALF) ((_Float16*)Cv)[(size_t)row * ldc + col] = (_Float16)v;
                    else          ((float*)Cv)[(size_t)row * ldc + col] = v;
                }
            }
    }
}

// ---------------------------------------------------------------------------
// MFMA flash attention v6: 64 q per wave (2x arithmetic intensity vs v5 —
// same 8 fragment loads/iter now feed 32 MFMAs). Key-split x2 partials.
// Grid: 512 blocks = (b,h) x 8 q-blocks(256) x 2 key-halves(1024).
// Zero barriers; per-wave-private es rows; S^T=mfma(kf,qf) so the E
// round-trip is contiguous half4 writes / half8 A-frag reads.
// ---------------------------------------------------------------------------
__global__ __launch_bounds__(256, 2) void attn_v6(const _Float16* __restrict__ qkh,
                                                  const _Float16* __restrict__ VT,
                                                  _Float16* __restrict__ NUM,
                                                  float* __restrict__ DEN) {
    __shared__ alignas(16) _Float16 es[4][64][40];
    const int bid = blockIdx.x;
    const int kh = bid & 1;
    const int qb = (bid >> 1) & 7;
    const int bh = bid >> 4;
    const int b = bh >> 3, h = bh & 7;
    const int t = threadIdx.x, lane = t & 63, wave = t >> 6;
    const int l16 = lane & 15, quad = lane >> 4;
    const float scale = 0.17677669529663687f;  // 32^-0.5
    const int bN = b * 2048;
    const int q0w = qb * 256 + wave * 64;
    const int kbeg = kh * 1024;

    // Q fragments (B-operand of S^T): 4 groups of 16 q, in regs all pass.
    half8_t qf[4];
    {
        const _Float16* qrow = qkh + (size_t)(bN + q0w + l16) * 512 + h * HDIM + quad * 8;
        #pragma unroll
        for (int g = 0; g < 4; ++g)
            qf[g] = *reinterpret_cast<const half8_t*>(qrow + (size_t)g * 16 * 512);
    }

    const _Float16* kbase = qkh + (size_t)(bN + l16) * 512 + 256 + h * HDIM + quad * 8;
    const _Float16* vbase = VT + (size_t)bh * HDIM * 2048 + (size_t)l16 * 2048 + quad * 8;

    float4_t num[4][2];
    #pragma unroll
    for (int g = 0; g < 4; ++g)
        #pragma unroll
        for (int dt = 0; dt < 2; ++dt) num[g][dt] = (float4_t){0.f, 0.f, 0.f, 0.f};
    float ds[4] = {0.f, 0.f, 0.f, 0.f};
    _Float16* esw = &es[wave][0][0];
    const float4_t z = {0.f, 0.f, 0.f, 0.f};

    for (int k0 = kbeg; k0 < kbeg + 1024; k0 += 64) {
        // K fragments: 4 x 16 keys; V fragments: 2 chunks x 2 hd-halves.
        const _Float16* kp = kbase + (size_t)k0 * 512;
        half8_t kf[4], vf[4];
        #pragma unroll
        for (int j = 0; j < 4; ++j)
            kf[j] = *reinterpret_cast<const half8_t*>(kp + (size_t)j * 16 * 512);
        const _Float16* vp = vbase + k0;
        vf[0] = *reinterpret_cast<const half8_t*>(vp);
        vf[1] = *reinterpret_cast<const half8_t*>(vp + (size_t)16 * 2048);
        vf[2] = *reinterpret_cast<const half8_t*>(vp + 32);
        vf[3] = *reinterpret_cast<const half8_t*>(vp + 32 + (size_t)16 * 2048);

        // S^T = K Q^T : lane holds S^T[key=kb*16+quad*4+r][q=q0w+g*16+l16]
        float4_t st[4][4];
        #pragma unroll
        for (int kb = 0; kb < 4; ++kb)
            #pragma unroll
            for (int g = 0; g < 4; ++g)
                st[kb][g] = __builtin_amdgcn_mfma_f32_16x16x32_f16(kf[kb], qf[g], z, 0, 0, 0);

        // e = exp(s*scale); accumulate denom; pack fp16 half4 per (kb,g).
        half4_t ep[4][4];
        #pragma unroll
        for (int kb = 0; kb < 4; ++kb)
            #pragma unroll
            for (int g = 0; g < 4; ++g)
                #pragma unroll
                for (int r = 0; r < 4; ++r) {
                    float e = __expf(st[kb][g][r] * scale);
                    ds[g] += e;
                    ep[kb][g][r] = (_Float16)e;
                }

        // Two 32-key chunks: E -> LDS (b64), E A-frags back (b128), PV MFMAs.
        #pragma unroll
        for (int s = 0; s < 2; ++s) {
            #pragma unroll
            for (int tt = 0; tt < 2; ++tt)
                #pragma unroll
                for (int g = 0; g < 4; ++g)
                    *reinterpret_cast<half4_t*>(
                        esw + (g * 16 + l16) * 40 + tt * 16 + quad * 4) = ep[s * 2 + tt][g];

            #pragma unroll
            for (int g = 0; g < 4; ++g) {
                half8_t ef = *reinterpret_cast<const half8_t*>(
                    esw + (g * 16 + l16) * 40 + quad * 8);
                num[g][0] = __builtin_amdgcn_mfma_f32_16x16x32_f16(ef, vf[s * 2],     num[g][0], 0, 0, 0);
                num[g][1] = __builtin_amdgcn_mfma_f32_16x16x32_f16(ef, vf[s * 2 + 1], num[g][1], 0, 0, 0);
            }
        }
    }

    // denom partials: sum the 4 key-quads per q column.
    #pragma unroll
    for (int g = 0; g < 4; ++g) {
        ds[g] += __shfl_xor(ds[g], 16, 64);
        ds[g] += __shfl_xor(ds[g], 32, 64);
    }

    // Store partial numerator (fp16, unnormalized) and partial denom (fp32).
    _Float16* ob = NUM + (size_t)kh * 2097152 + (size_t)(bN + q0w) * DIM + h * HDIM;
    #pragma unroll
    for (int g = 0; g < 4; ++g)
        #pragma unroll
        for (int r = 0; r < 4; ++r) {
            size_t ro = (size_t)(g * 16 + quad * 4 + r) * DIM;
            ob[ro + l16]      = (_Float16)num[g][0][r];
            ob[ro + 16 + l16] = (_Float16)num[g][1][r];
        }
    if (quad == 0) {
        #pragma unroll
        for (int g = 0; g < 4; ++g)
            DEN[kh * 65536 + bh * 2048 + q0w + g * 16 + l16] = ds[g];
    }
}

// ---------------------------------------------------------------------------
// combine: attnh = (NUM0 + NUM1) * rcp(DEN0 + DEN1 + 1e-6), elementwise fp16.
// ---------------------------------------------------------------------------
__global__ __launch_bounds__(256) void combine(const _Float16* __restrict__ NUM,
                                               const float* __restrict__ DEN,
                                               _Float16* __restrict__ attnh) {
    const size_t idx = ((size_t)blockIdx.x * 256 + threadIdx.x) * 8;
    const int row = (int)(idx >> 8);
    const int c = (int)(idx & 255);
    const int b = row >> 11, tok = row & 2047, h = c >> 5;
    const int di = (b * 8 + h) * 2048 + tok;
    float rcp = 1.0f / (DEN[di] + DEN[di + 65536] + 1e-6f);
    half8_t n0 = *reinterpret_cast<const half8_t*>(NUM + idx);
    half8_t n1 = *reinterpret_cast<const half8_t*>(NUM + idx + 2097152);
    *reinterpret_cast<half8_t*>(attnh + idx) = (n0 + n1) * (_Float16)rcp;
}

extern "C" void kernel_launch(void* const* d_in, const int* in_sizes, int n_in,
                              void* d_out, int out_size, void* d_ws, size_t ws_size,
                              hipStream_t stream) {
    const float* x    = (const float*)d_in[0];
    const float* Wqkv = (const float*)d_in[1];
    const float* Wout = (const float*)d_in[2];
    const float* bout = (const float*)d_in[3];
    float* out = (float*)d_out;
    const int M = 8192;

    _Float16* xh    = (_Float16*)d_ws;                 // [8192,256]
    _Float16* WqT   = xh + (size_t)M * DIM;            // [768,256]
    _Float16* WoT   = WqT + 768 * 256;                 // [256,256]
    _Float16* qkh   = WoT + 256 * 256;                 // [8192,512]  (Q|K)
    _Float16* vt    = qkh + (size_t)M * 512;           // [4][8][32][2048] V^T
    _Float16* NUM   = vt + (size_t)32 * HDIM * 2048;   // [2][8192,256] partials
    float*    DEN   = (float*)(NUM + (size_t)2 * M * DIM);  // [2][65536]
    _Float16* attnh = (_Float16*)(DEN + 2 * 65536);    // [8192,256]

    hipLaunchKernelGGL(prep, dim3(1280), dim3(256), 0, stream, x, Wqkv, Wout, xh, WqT, WoT);
    // qkv GEMM (LDS-staged): Q,K -> qkh (ldc 512); V -> vt transposed.
    hipLaunchKernelGGL((gemm_h<true, true>), dim3(6, 64), dim3(256), 0, stream,
                       xh, WqT, (const float*)nullptr, (void*)qkh, vt, M, 768, DIM, 512);
    // attention, key-split x2 -> partials (64 q/wave)
    hipLaunchKernelGGL(attn_v6, dim3(512), dim3(256), 0, stream, qkh, vt, NUM, DEN);
    // combine partials -> attnh
    hipLaunchKernelGGL(combine, dim3(1024), dim3(256), 0, stream, NUM, DEN, attnh);
    // out = attnh @ Wout + bout (fp32 out)
    hipLaunchKernelGGL((gemm_h<false, false>), dim3(2, 64), dim3(256), 0, stream,
                       attnh, WoT, bout, (void*)out, (_Float16*)nullptr, M, DIM, DIM, DIM);
}